// Round 2
// baseline (916.050 us; speedup 1.0000x reference)
//
#include <hip/hip_runtime.h>
#include <hip/hip_bf16.h>

typedef unsigned short u16;
typedef __bf16 bf16x8 __attribute__((ext_vector_type(8)));
typedef float f32x4 __attribute__((ext_vector_type(4)));

#define DIM 2048
#define SEQ 2048
#define HEADS 16
#define DH 128
#define FUSED_OUT 18688   // 2048 q + 128 k + 128 v + 16384 ff
#define FF_INNER 8192
#define KOFF 2048
#define VOFF 2176
#define FFOFF 2304
#define AE_LD 10240       // 2048 attn + 8192 ffa concat-K for final GEMM

// ---- workspace layout (bytes). Total = 162,004,992 (~155 MB).
// Phase 1: xn @0 (8MB), wfT @8388608 (73MB). After proj GEMM both are dead:
// Phase 2 reuses that region for BtE @0 (40MB) and Ae @41943040 (40MB).
#define WS_XN   0
#define WS_WFT  8388608
#define WS_PROJ 84934656
#define WS_VT   161480704
#define WS_BTE  0
#define WS_AE   41943040

__device__ __forceinline__ float b2f(u16 u) {
  union { unsigned int i; float f; } c; c.i = ((unsigned int)u) << 16; return c.f;
}
__device__ __forceinline__ u16 f2b(float f) {  // RNE, matches np/jax bf16 cast
  union { float f; unsigned int i; } c; c.f = f;
  return (u16)((c.i + 0x7fffu + ((c.i >> 16) & 1u)) >> 16);
}
// async global->LDS, 16B per lane; LDS dest = wave-uniform base + lane*16
__device__ __forceinline__ void async16(void* lds, const void* g) {
  __builtin_amdgcn_global_load_lds((const __attribute__((address_space(1))) unsigned int*)g,
                                   (__attribute__((address_space(3))) unsigned int*)lds,
                                   16, 0, 0);
}

union U8 { uint4 v; u16 s[8]; };

// ---------------- LayerNorm: one block per row; f32 in -> bf16 out ----------------
__global__ void __launch_bounds__(256) ln_kernel(const float* __restrict__ x,
                                                 const float* __restrict__ gamma,
                                                 u16* __restrict__ xn) {
  const int row = blockIdx.x, tid = threadIdx.x;
  const int lane = tid & 63, wv = tid >> 6;
  float v[8], s1 = 0.f, s2 = 0.f;
  {
    float4 a0 = *(const float4*)(x + (size_t)row * DIM + tid * 8);
    float4 a1 = *(const float4*)(x + (size_t)row * DIM + tid * 8 + 4);
    v[0] = a0.x; v[1] = a0.y; v[2] = a0.z; v[3] = a0.w;
    v[4] = a1.x; v[5] = a1.y; v[6] = a1.z; v[7] = a1.w;
  }
#pragma unroll
  for (int i = 0; i < 8; ++i) { s1 += v[i]; s2 += v[i] * v[i]; }
#pragma unroll
  for (int off = 32; off > 0; off >>= 1) {
    s1 += __shfl_down(s1, off, 64);
    s2 += __shfl_down(s2, off, 64);
  }
  __shared__ float r1[4], r2[4];
  if (lane == 0) { r1[wv] = s1; r2[wv] = s2; }
  __syncthreads();
  s1 = r1[0] + r1[1] + r1[2] + r1[3];
  s2 = r2[0] + r2[1] + r2[2] + r2[3];
  const float inv = 1.0f / DIM;
  const float mu = s1 * inv;
  const float var = s2 * inv - mu * mu;
  const float rs = rsqrtf(var + 1e-5f);
  float4 g0 = *(const float4*)(gamma + tid * 8);
  float4 g1 = *(const float4*)(gamma + tid * 8 + 4);
  const float gm[8] = {g0.x, g0.y, g0.z, g0.w, g1.x, g1.y, g1.z, g1.w};
  U8 o;
#pragma unroll
  for (int i = 0; i < 8; ++i) o.s[i] = f2b((v[i] - mu) * rs * gm[i]);
  *(uint4*)(xn + (size_t)row * DIM + tid * 8) = o.v;
}

// ------------- transpose f32 -> bf16: out[c*ldout + r] = bf16(in[r*ldin + c]) -------------
__global__ void __launch_bounds__(256) transpose_f2b(const float* __restrict__ in,
                                                     u16* __restrict__ out,
                                                     int ldin, int ldout) {
  __shared__ u16 t[32][33];
  const int tx = threadIdx.x, ty = threadIdx.y;
  const int r0 = blockIdx.y * 32, c0 = blockIdx.x * 32;
#pragma unroll
  for (int i = 0; i < 4; ++i)
    t[ty + i * 8][tx] = f2b(in[(size_t)(r0 + ty + i * 8) * ldin + c0 + tx]);
  __syncthreads();
#pragma unroll
  for (int i = 0; i < 4; ++i)
    out[(size_t)(c0 + ty + i * 8) * ldout + r0 + tx] = t[tx][ty + i * 8];
}

// ------------- transpose bf16 -> bf16 (for V^T) -------------
__global__ void __launch_bounds__(256) transpose_u16(const u16* __restrict__ in,
                                                     u16* __restrict__ out,
                                                     int ldin, int ldout) {
  __shared__ u16 t[32][33];
  const int tx = threadIdx.x, ty = threadIdx.y;
  const int r0 = blockIdx.y * 32, c0 = blockIdx.x * 32;
#pragma unroll
  for (int i = 0; i < 4; ++i)
    t[ty + i * 8][tx] = in[(size_t)(r0 + ty + i * 8) * ldin + c0 + tx];
  __syncthreads();
#pragma unroll
  for (int i = 0; i < 4; ++i)
    out[(size_t)(c0 + ty + i * 8) * ldout + r0 + tx] = t[tx][ty + i * 8];
}

// ---------------- GEMM: C(MxN) = A(MxK) @ Bt(NxK)^T, bf16 in, f32 acc ----------
// m97 structure: 128x128 tile, BK=64, 4 waves (2x2 of 64x64), global_load_lds w=16.
// OUTF32: store float (final output); else store bf16.
template <bool OUTF32>
__global__ void __launch_bounds__(256) gemm_bt(const u16* __restrict__ A,
                                               const u16* __restrict__ Bt,
                                               void* __restrict__ Cv,
                                               int K, int lda, int ldb, int ldc) {
  __shared__ alignas(16) u16 sA[128 * 64];
  __shared__ alignas(16) u16 sB[128 * 64];
  const int tid = threadIdx.x;
  const int lane = tid & 63, wv = tid >> 6;
  const int lhalf = lane & 15, lgrp = lane >> 4;
  const int m0 = blockIdx.y * 128, n0 = blockIdx.x * 128;
  const int wr = (wv >> 1) * 64, wc = (wv & 1) * 64;
  const f32x4 fzero = {0.f, 0.f, 0.f, 0.f};

  f32x4 acc[4][4];
#pragma unroll
  for (int i = 0; i < 4; ++i)
#pragma unroll
    for (int j = 0; j < 4; ++j) acc[i][j] = fzero;

  for (int k0 = 0; k0 < K; k0 += 64) {
#pragma unroll
    for (int c = 0; c < 4; ++c) {
      const int l = c * 4096 + wv * 1024 + lane * 16;  // byte offset in 16KB tile
      const int row = l >> 7, colb = l & 127;          // tile row / byte-col (128B rows)
      const int ldsoff = (c * 4096 + wv * 1024) >> 1;  // wave-uniform LDS base (u16 idx)
      async16(&sA[ldsoff], A + (size_t)(m0 + row) * lda + k0 + (colb >> 1));
      async16(&sB[ldsoff], Bt + (size_t)(n0 + row) * ldb + k0 + (colb >> 1));
    }
    __syncthreads();  // waits vmcnt(0): global_load_lds drained
#pragma unroll
    for (int kk = 0; kk < 64; kk += 32) {
      bf16x8 af[4], bfr[4];
#pragma unroll
      for (int i = 0; i < 4; ++i)
        af[i] = *(const bf16x8*)&sA[(wr + i * 16 + lhalf) * 64 + kk + lgrp * 8];
#pragma unroll
      for (int j = 0; j < 4; ++j)
        bfr[j] = *(const bf16x8*)&sB[(wc + j * 16 + lhalf) * 64 + kk + lgrp * 8];
#pragma unroll
      for (int i = 0; i < 4; ++i)
#pragma unroll
        for (int j = 0; j < 4; ++j)
          acc[i][j] = __builtin_amdgcn_mfma_f32_16x16x32_bf16(af[i], bfr[j], acc[i][j], 0, 0, 0);
    }
    __syncthreads();
  }
  // C/D layout (verified m89/m91): col = lane&15, row = (lane>>4)*4 + reg
#pragma unroll
  for (int i = 0; i < 4; ++i)
#pragma unroll
    for (int j = 0; j < 4; ++j)
#pragma unroll
      for (int t = 0; t < 4; ++t) {
        const int row = m0 + wr + i * 16 + lgrp * 4 + t;
        const int col = n0 + wc + j * 16 + lhalf;
        if (OUTF32) ((float*)Cv)[(size_t)row * ldc + col] = acc[i][j][t];
        else ((u16*)Cv)[(size_t)row * ldc + col] = f2b(acc[i][j][t]);
      }
}

// ---------------- Flash MQA attention ----------------
// Block = 64 q-rows (4 waves x 16 rows), head = blockIdx.y, q-tile = blockIdx.x.
// Each wave does its own online softmax over its 16 rows (shfl within 16-lane groups).
__global__ void __launch_bounds__(256) attn_kernel(const u16* __restrict__ proj,
                                                   const u16* __restrict__ Vt,
                                                   u16* __restrict__ Ae) {
  const int h = blockIdx.y, qi = blockIdx.x;
  const int tid = threadIdx.x;
  const int lane = tid & 63, wv = tid >> 6;
  const int lhalf = lane & 15, lgrp = lane >> 4;

  __shared__ alignas(16) u16 Ks[128 * 128];       // K tile: [j][d]
  __shared__ alignas(16) u16 Vts[128 * 128];      // V^T tile: [d][j]
  __shared__ alignas(16) u16 Ps[4][16 * 128];     // per-wave P scratch (C->A layout)

  // Q fragments live in regs for the whole kernel (wave's 16 rows x 128 d)
  bf16x8 aq[4];
  {
    const u16* gq = proj + (size_t)(qi * 64 + wv * 16 + lhalf) * FUSED_OUT + h * DH;
#pragma unroll
    for (int kk = 0; kk < 4; ++kk) aq[kk] = *(const bf16x8*)(gq + kk * 32 + lgrp * 8);
  }
  const f32x4 fzero = {0.f, 0.f, 0.f, 0.f};
  f32x4 o[8];
#pragma unroll
  for (int i = 0; i < 8; ++i) o[i] = fzero;
  float mrow[4] = {-__builtin_inff(), -__builtin_inff(), -__builtin_inff(), -__builtin_inff()};
  float lrow[4] = {0.f, 0.f, 0.f, 0.f};
  const float scale = 0.088388347648318447f;  // 128^-0.5
  const int jmax = (qi * 64 + 63) >> 7;

  for (int jt = 0; jt <= jmax; ++jt) {
    __syncthreads();  // protect Ks/Vts from prior iter's readers
#pragma unroll
    for (int i = 0; i < 8; ++i) {
      const int e = (i * 256 + tid) * 8;
      const int r = e >> 7, c = e & 127;
      *(uint4*)&Ks[r * 128 + c] = *(const uint4*)(proj + (size_t)(jt * 128 + r) * FUSED_OUT + KOFF + c);
      *(uint4*)&Vts[r * 128 + c] = *(const uint4*)(Vt + (size_t)r * SEQ + jt * 128 + c);
    }
    __syncthreads();
    // S (16x128) = Q_wave @ K^T
    f32x4 s[8];
#pragma unroll
    for (int sub = 0; sub < 8; ++sub) {
      f32x4 a = fzero;
#pragma unroll
      for (int kk = 0; kk < 4; ++kk) {
        bf16x8 bk = *(const bf16x8*)&Ks[(sub * 16 + lhalf) * 128 + kk * 32 + lgrp * 8];
        a = __builtin_amdgcn_mfma_f32_16x16x32_bf16(aq[kk], bk, a, 0, 0, 0);
      }
      s[sub] = a;
    }
    const int row_g = qi * 64 + wv * 16 + lgrp * 4;  // + t
    const int col_b = jt * 128 + lhalf;              // + sub*16
#pragma unroll
    for (int t = 0; t < 4; ++t) {
      float mx = -__builtin_inff();
#pragma unroll
      for (int sub = 0; sub < 8; ++sub) {
        float v = s[sub][t] * scale;
        if (col_b + sub * 16 > row_g + t) v = -__builtin_inff();  // causal
        s[sub][t] = v;
        mx = fmaxf(mx, v);
      }
      mx = fmaxf(mx, __shfl_xor(mx, 1, 64));
      mx = fmaxf(mx, __shfl_xor(mx, 2, 64));
      mx = fmaxf(mx, __shfl_xor(mx, 4, 64));
      mx = fmaxf(mx, __shfl_xor(mx, 8, 64));
      const float mnew = fmaxf(mrow[t], mx);
      const float alpha = __expf(mrow[t] - mnew);  // first iter: exp(-inf)=0
      mrow[t] = mnew;
      float ls = 0.f;
#pragma unroll
      for (int sub = 0; sub < 8; ++sub) {
        const float p = __expf(s[sub][t] - mnew);
        s[sub][t] = p;
        ls += p;
      }
      ls += __shfl_xor(ls, 1, 64);
      ls += __shfl_xor(ls, 2, 64);
      ls += __shfl_xor(ls, 4, 64);
      ls += __shfl_xor(ls, 8, 64);
      lrow[t] = lrow[t] * alpha + ls;
#pragma unroll
      for (int sub = 0; sub < 8; ++sub) {
        o[sub][t] *= alpha;
        // C-layout -> A-layout transform via LDS (m120 pattern)
        Ps[wv][(lgrp * 4 + t) * 128 + sub * 16 + lhalf] = f2b(s[sub][t]);
      }
    }
    __syncthreads();  // make P visible across lanes (cheap safety barrier)
    // O += P (16x128) @ V (128x128): A from Ps, B^T from Vts
#pragma unroll
    for (int kk = 0; kk < 4; ++kk) {
      bf16x8 ap = *(const bf16x8*)&Ps[wv][lhalf * 128 + kk * 32 + lgrp * 8];
#pragma unroll
      for (int sub = 0; sub < 8; ++sub) {
        bf16x8 bv = *(const bf16x8*)&Vts[(sub * 16 + lhalf) * 128 + kk * 32 + lgrp * 8];
        o[sub] = __builtin_amdgcn_mfma_f32_16x16x32_bf16(ap, bv, o[sub], 0, 0, 0);
      }
    }
  }
#pragma unroll
  for (int sub = 0; sub < 8; ++sub)
#pragma unroll
    for (int t = 0; t < 4; ++t) {
      const int row = qi * 64 + wv * 16 + lgrp * 4 + t;
      const int col = h * DH + sub * 16 + lhalf;
      Ae[(size_t)row * AE_LD + col] = f2b(o[sub][t] / lrow[t]);
    }
}

// ---------------- SiLU gate: Ae[:, 2048+j] = silu(gate)*ff_x ----------------
__global__ void __launch_bounds__(256) ffa_kernel(const u16* __restrict__ proj,
                                                  u16* __restrict__ Ae) {
  const size_t idx = (size_t)blockIdx.x * 256 + threadIdx.x;
  const size_t e = idx * 8;
  const int row = (int)(e >> 13);   // /8192
  const int j = (int)(e & 8191);
  const u16* base = proj + (size_t)row * FUSED_OUT + FFOFF;
  U8 xr, gr, os;
  xr.v = *(const uint4*)(base + j);
  gr.v = *(const uint4*)(base + FF_INNER + j);
#pragma unroll
  for (int i = 0; i < 8; ++i) {
    const float g = b2f(gr.s[i]);
    const float sg = g / (1.f + __expf(-g));
    os.s[i] = f2b(sg * b2f(xr.s[i]));
  }
  *(uint4*)(Ae + (size_t)row * AE_LD + 2048 + j) = os.v;
}

extern "C" void kernel_launch(void* const* d_in, const int* in_sizes, int n_in,
                              void* d_out, int out_size, void* d_ws, size_t ws_size,
                              hipStream_t stream) {
  const float* x       = (const float*)d_in[0];
  const float* gamma   = (const float*)d_in[1];
  const float* w_fused = (const float*)d_in[2];
  const float* w_attn  = (const float*)d_in[3];
  const float* w_ff    = (const float*)d_in[4];
  float* out = (float*)d_out;
  char* ws = (char*)d_ws;
  u16* xn   = (u16*)(ws + WS_XN);
  u16* wfT  = (u16*)(ws + WS_WFT);
  u16* proj = (u16*)(ws + WS_PROJ);
  u16* Vt   = (u16*)(ws + WS_VT);
  u16* BtE  = (u16*)(ws + WS_BTE);   // aliases xn/wfT (dead after proj GEMM)
  u16* Ae   = (u16*)(ws + WS_AE);

  // Phase 1: LN + weight transpose(+cast) + fused projection GEMM
  ln_kernel<<<dim3(2048), dim3(256), 0, stream>>>(x, gamma, xn);
  transpose_f2b<<<dim3(584, 64), dim3(32, 8), 0, stream>>>(w_fused, wfT, FUSED_OUT, DIM);
  gemm_bt<false><<<dim3(146, 16), dim3(256), 0, stream>>>(xn, wfT, proj, DIM, DIM, DIM, FUSED_OUT);

  // Phase 2: attention + gate, into concat-K activation buffer
  transpose_u16<<<dim3(4, 64), dim3(32, 8), 0, stream>>>(proj + VOFF, Vt, FUSED_OUT, SEQ);
  transpose_f2b<<<dim3(64, 64), dim3(32, 8), 0, stream>>>(w_attn, BtE, DIM, AE_LD);
  transpose_f2b<<<dim3(64, 256), dim3(32, 8), 0, stream>>>(w_ff, BtE + 2048, DIM, AE_LD);
  attn_kernel<<<dim3(32, 16), dim3(256), 0, stream>>>(proj, Vt, Ae);
  ffa_kernel<<<dim3(8192), dim3(256), 0, stream>>>(proj, Ae);

  // Phase 3: fused (attn_out + ff_out) via one concat-K GEMM straight to d_out
  gemm_bt<true><<<dim3(16, 16), dim3(256), 0, stream>>>(Ae, BtE, out, AE_LD, AE_LD, AE_LD, DIM);
}

// Round 3
// 821.690 us; speedup vs baseline: 1.1148x; 1.1148x over previous
//
#include <hip/hip_runtime.h>
#include <hip/hip_bf16.h>

typedef unsigned short u16;
typedef __bf16 bf16x8 __attribute__((ext_vector_type(8)));
typedef float f32x4 __attribute__((ext_vector_type(4)));

#define DIM 2048
#define SEQ 2048
#define HEADS 16
#define DH 128
#define FUSED_OUT 18688   // 2048 q + 128 k + 128 v + 16384 ff
#define FF_INNER 8192
#define KOFF 2048
#define VOFF 2176
#define FFOFF 2304
#define AE_LD 10240       // 2048 attn + 8192 ffa concat-K for final GEMM

// ---- workspace layout (bytes). Total = 162,004,992 (~155 MB).
#define WS_XN   0
#define WS_WFT  8388608
#define WS_PROJ 84934656
#define WS_VT   161480704
#define WS_BTE  0
#define WS_AE   41943040

__device__ __forceinline__ float b2f(u16 u) {
  union { unsigned int i; float f; } c; c.i = ((unsigned int)u) << 16; return c.f;
}
__device__ __forceinline__ u16 f2b(float f) {  // RNE, matches np/jax bf16 cast
  union { float f; unsigned int i; } c; c.f = f;
  return (u16)((c.i + 0x7fffu + ((c.i >> 16) & 1u)) >> 16);
}
// async global->LDS, 16B per lane; LDS dest = wave-uniform base + lane*16
__device__ __forceinline__ void async16(void* lds, const void* g) {
  __builtin_amdgcn_global_load_lds((const __attribute__((address_space(1))) unsigned int*)g,
                                   (__attribute__((address_space(3))) unsigned int*)lds,
                                   16, 0, 0);
}

union U8 { uint4 v; u16 s[8]; };

// ---------------- LayerNorm: one block per row; f32 in -> bf16 out ----------------
__global__ void __launch_bounds__(256) ln_kernel(const float* __restrict__ x,
                                                 const float* __restrict__ gamma,
                                                 u16* __restrict__ xn) {
  const int row = blockIdx.x, tid = threadIdx.x;
  const int lane = tid & 63, wv = tid >> 6;
  float v[8], s1 = 0.f, s2 = 0.f;
  {
    float4 a0 = *(const float4*)(x + (size_t)row * DIM + tid * 8);
    float4 a1 = *(const float4*)(x + (size_t)row * DIM + tid * 8 + 4);
    v[0] = a0.x; v[1] = a0.y; v[2] = a0.z; v[3] = a0.w;
    v[4] = a1.x; v[5] = a1.y; v[6] = a1.z; v[7] = a1.w;
  }
#pragma unroll
  for (int i = 0; i < 8; ++i) { s1 += v[i]; s2 += v[i] * v[i]; }
#pragma unroll
  for (int off = 32; off > 0; off >>= 1) {
    s1 += __shfl_down(s1, off, 64);
    s2 += __shfl_down(s2, off, 64);
  }
  __shared__ float r1[4], r2[4];
  if (lane == 0) { r1[wv] = s1; r2[wv] = s2; }
  __syncthreads();
  s1 = r1[0] + r1[1] + r1[2] + r1[3];
  s2 = r2[0] + r2[1] + r2[2] + r2[3];
  const float inv = 1.0f / DIM;
  const float mu = s1 * inv;
  const float var = s2 * inv - mu * mu;
  const float rs = rsqrtf(var + 1e-5f);
  float4 g0 = *(const float4*)(gamma + tid * 8);
  float4 g1 = *(const float4*)(gamma + tid * 8 + 4);
  const float gm[8] = {g0.x, g0.y, g0.z, g0.w, g1.x, g1.y, g1.z, g1.w};
  U8 o;
#pragma unroll
  for (int i = 0; i < 8; ++i) o.s[i] = f2b((v[i] - mu) * rs * gm[i]);
  *(uint4*)(xn + (size_t)row * DIM + tid * 8) = o.v;
}

// ------------- transpose f32 -> bf16: out[c*ldout + r] = bf16(in[r*ldin + c]) -------------
__global__ void __launch_bounds__(256) transpose_f2b(const float* __restrict__ in,
                                                     u16* __restrict__ out,
                                                     int ldin, int ldout) {
  __shared__ u16 t[32][33];
  const int tx = threadIdx.x, ty = threadIdx.y;
  const int r0 = blockIdx.y * 32, c0 = blockIdx.x * 32;
#pragma unroll
  for (int i = 0; i < 4; ++i)
    t[ty + i * 8][tx] = f2b(in[(size_t)(r0 + ty + i * 8) * ldin + c0 + tx]);
  __syncthreads();
#pragma unroll
  for (int i = 0; i < 4; ++i)
    out[(size_t)(c0 + ty + i * 8) * ldout + r0 + tx] = t[tx][ty + i * 8];
}

// ------------- transpose bf16 -> bf16 (for V^T) -------------
__global__ void __launch_bounds__(256) transpose_u16(const u16* __restrict__ in,
                                                     u16* __restrict__ out,
                                                     int ldin, int ldout) {
  __shared__ u16 t[32][33];
  const int tx = threadIdx.x, ty = threadIdx.y;
  const int r0 = blockIdx.y * 32, c0 = blockIdx.x * 32;
#pragma unroll
  for (int i = 0; i < 4; ++i)
    t[ty + i * 8][tx] = in[(size_t)(r0 + ty + i * 8) * ldin + c0 + tx];
  __syncthreads();
#pragma unroll
  for (int i = 0; i < 4; ++i)
    out[(size_t)(c0 + ty + i * 8) * ldout + r0 + tx] = t[tx][ty + i * 8];
}

// ---------------- GEMM: C(MxN) = A(MxK) @ Bt(NxK)^T, bf16 in, f32 acc ----------
// m97 structure: 128x128 tile, BK=64, 4 waves (2x2 of 64x64), global_load_lds w=16.
// Grid: x = M-tile (fast-varying -> consecutive blocks share the B tile), y = N-tile.
// LDS is XOR-swizzled: 16B block column b stored at (b ^ (row&7)) -> 2-way (free) banks.
// OUTF32: store float (final output); else store bf16.
template <bool OUTF32>
__global__ void __launch_bounds__(256) gemm_bt(const u16* __restrict__ A,
                                               const u16* __restrict__ Bt,
                                               void* __restrict__ Cv,
                                               int K, int lda, int ldb, int ldc) {
  __shared__ alignas(16) u16 sA[128 * 64];
  __shared__ alignas(16) u16 sB[128 * 64];
  const int tid = threadIdx.x;
  const int lane = tid & 63, wv = tid >> 6;
  const int lhalf = lane & 15, lgrp = lane >> 4;
  const int m0 = blockIdx.x * 128, n0 = blockIdx.y * 128;
  const int wr = (wv >> 1) * 64, wc = (wv & 1) * 64;
  const f32x4 fzero = {0.f, 0.f, 0.f, 0.f};

  // staging map: lane covers row = c*32 + wv*8 + (lane>>3); its LDS slot is 16B-block
  // (lane&7) of that row, which holds global 16B-block ((lane&7) ^ (row&7)).
  const int srow = lane >> 3;              // row-within-8 = row&7
  const int scol = ((lane & 7) ^ srow) * 8;  // swizzled global col (u16)
  const int key = lhalf & 7;               // fragment-read XOR key (= row&7)

  f32x4 acc[4][4];
#pragma unroll
  for (int i = 0; i < 4; ++i)
#pragma unroll
    for (int j = 0; j < 4; ++j) acc[i][j] = fzero;

  for (int k0 = 0; k0 < K; k0 += 64) {
#pragma unroll
    for (int c = 0; c < 4; ++c) {
      const int row = c * 32 + wv * 8 + srow;
      const int ldsoff = (c * 4096 + wv * 1024) >> 1;  // wave-uniform LDS base (u16 idx)
      async16(&sA[ldsoff], A + (size_t)(m0 + row) * lda + k0 + scol);
      async16(&sB[ldsoff], Bt + (size_t)(n0 + row) * ldb + k0 + scol);
    }
    __syncthreads();  // waits vmcnt(0): global_load_lds drained
#pragma unroll
    for (int kk = 0; kk < 64; kk += 32) {
      bf16x8 af[4], bfr[4];
#pragma unroll
      for (int i = 0; i < 4; ++i)
        af[i] = *(const bf16x8*)&sA[(wr + i * 16 + lhalf) * 64 + ((((kk >> 3) + lgrp) ^ key) << 3)];
#pragma unroll
      for (int j = 0; j < 4; ++j)
        bfr[j] = *(const bf16x8*)&sB[(wc + j * 16 + lhalf) * 64 + ((((kk >> 3) + lgrp) ^ key) << 3)];
#pragma unroll
      for (int i = 0; i < 4; ++i)
#pragma unroll
        for (int j = 0; j < 4; ++j)
          acc[i][j] = __builtin_amdgcn_mfma_f32_16x16x32_bf16(af[i], bfr[j], acc[i][j], 0, 0, 0);
    }
    __syncthreads();
  }
  // C/D layout (verified m89/m91): col = lane&15, row = (lane>>4)*4 + reg
#pragma unroll
  for (int i = 0; i < 4; ++i)
#pragma unroll
    for (int j = 0; j < 4; ++j)
#pragma unroll
      for (int t = 0; t < 4; ++t) {
        const int row = m0 + wr + i * 16 + lgrp * 4 + t;
        const int col = n0 + wc + j * 16 + lhalf;
        if (OUTF32) ((float*)Cv)[(size_t)row * ldc + col] = acc[i][j][t];
        else ((u16*)Cv)[(size_t)row * ldc + col] = f2b(acc[i][j][t]);
      }
}

// ---------------- Flash MQA attention ----------------
// Block = 64 q-rows (4 waves x 16 rows), head = blockIdx.y, q-tile = blockIdx.x.
// Ks/Vts/Ps all XOR-swizzled (16B block b at b ^ (row&7)) to kill b128 bank conflicts.
__global__ void __launch_bounds__(256) attn_kernel(const u16* __restrict__ proj,
                                                   const u16* __restrict__ Vt,
                                                   u16* __restrict__ Ae) {
  const int h = blockIdx.y, qi = blockIdx.x;
  const int tid = threadIdx.x;
  const int lane = tid & 63, wv = tid >> 6;
  const int lhalf = lane & 15, lgrp = lane >> 4;
  const int key = lhalf & 7;

  __shared__ alignas(16) u16 Ks[128 * 128];       // K tile: [j][d], swizzled
  __shared__ alignas(16) u16 Vts[128 * 128];      // V^T tile: [d][j], swizzled
  __shared__ alignas(16) u16 Ps[4][16 * 128];     // per-wave P scratch, swizzled

  // Q fragments live in regs for the whole kernel (wave's 16 rows x 128 d)
  bf16x8 aq[4];
  {
    const u16* gq = proj + (size_t)(qi * 64 + wv * 16 + lhalf) * FUSED_OUT + h * DH;
#pragma unroll
    for (int kk = 0; kk < 4; ++kk) aq[kk] = *(const bf16x8*)(gq + kk * 32 + lgrp * 8);
  }
  const f32x4 fzero = {0.f, 0.f, 0.f, 0.f};
  f32x4 o[8];
#pragma unroll
  for (int i = 0; i < 8; ++i) o[i] = fzero;
  float mrow[4] = {-__builtin_inff(), -__builtin_inff(), -__builtin_inff(), -__builtin_inff()};
  float lrow[4] = {0.f, 0.f, 0.f, 0.f};
  const float scale = 0.088388347648318447f;  // 128^-0.5
  const int jmax = (qi * 64 + 63) >> 7;

  for (int jt = 0; jt <= jmax; ++jt) {
    __syncthreads();  // protect Ks/Vts from prior iter's readers
#pragma unroll
    for (int i = 0; i < 8; ++i) {
      const int blk = i * 256 + tid;     // 16B-block index in the 128x16-block tile
      const int r = blk >> 4;
      const int b = blk & 15;
      const int c = (b ^ (r & 7)) * 8;   // swizzled LDS col (u16)
      *(uint4*)&Ks[r * 128 + c] = *(const uint4*)(proj + (size_t)(jt * 128 + r) * FUSED_OUT + KOFF + b * 8);
      *(uint4*)&Vts[r * 128 + c] = *(const uint4*)(Vt + (size_t)r * SEQ + jt * 128 + b * 8);
    }
    __syncthreads();
    // S (16x128) = Q_wave @ K^T
    f32x4 s[8];
#pragma unroll
    for (int sub = 0; sub < 8; ++sub) {
      f32x4 a = fzero;
#pragma unroll
      for (int kk = 0; kk < 4; ++kk) {
        bf16x8 bk = *(const bf16x8*)&Ks[(sub * 16 + lhalf) * 128 + (((kk * 4 + lgrp) ^ key) << 3)];
        a = __builtin_amdgcn_mfma_f32_16x16x32_bf16(aq[kk], bk, a, 0, 0, 0);
      }
      s[sub] = a;
    }
    const int row_g = qi * 64 + wv * 16 + lgrp * 4;  // + t
    const int col_b = jt * 128 + lhalf;              // + sub*16
#pragma unroll
    for (int t = 0; t < 4; ++t) {
      float mx = -__builtin_inff();
#pragma unroll
      for (int sub = 0; sub < 8; ++sub) {
        float v = s[sub][t] * scale;
        if (col_b + sub * 16 > row_g + t) v = -__builtin_inff();  // causal
        s[sub][t] = v;
        mx = fmaxf(mx, v);
      }
      mx = fmaxf(mx, __shfl_xor(mx, 1, 64));
      mx = fmaxf(mx, __shfl_xor(mx, 2, 64));
      mx = fmaxf(mx, __shfl_xor(mx, 4, 64));
      mx = fmaxf(mx, __shfl_xor(mx, 8, 64));
      const float mnew = fmaxf(mrow[t], mx);
      const float alpha = __expf(mrow[t] - mnew);  // first iter: exp(-inf)=0
      mrow[t] = mnew;
      float ls = 0.f;
#pragma unroll
      for (int sub = 0; sub < 8; ++sub) {
        const float p = __expf(s[sub][t] - mnew);
        s[sub][t] = p;
        ls += p;
      }
      ls += __shfl_xor(ls, 1, 64);
      ls += __shfl_xor(ls, 2, 64);
      ls += __shfl_xor(ls, 4, 64);
      ls += __shfl_xor(ls, 8, 64);
      lrow[t] = lrow[t] * alpha + ls;
      // C-layout -> A-layout via LDS (m120), swizzled store
      const int prow = lgrp * 4 + t;
      const int pkey = prow & 7;
#pragma unroll
      for (int sub = 0; sub < 8; ++sub) {
        o[sub][t] *= alpha;
        const int b = sub * 2 + (lhalf >> 3);
        Ps[wv][prow * 128 + ((b ^ pkey) << 3) + (lhalf & 7)] = f2b(s[sub][t]);
      }
    }
    __syncthreads();  // make P visible across lanes (cheap safety barrier)
    // O += P (16x128) @ V (128x128): A from Ps, B^T from Vts
#pragma unroll
    for (int kk = 0; kk < 4; ++kk) {
      bf16x8 ap = *(const bf16x8*)&Ps[wv][lhalf * 128 + (((kk * 4 + lgrp) ^ key) << 3)];
#pragma unroll
      for (int sub = 0; sub < 8; ++sub) {
        bf16x8 bv = *(const bf16x8*)&Vts[(sub * 16 + lhalf) * 128 + (((kk * 4 + lgrp) ^ key) << 3)];
        o[sub] = __builtin_amdgcn_mfma_f32_16x16x32_bf16(ap, bv, o[sub], 0, 0, 0);
      }
    }
  }
#pragma unroll
  for (int sub = 0; sub < 8; ++sub)
#pragma unroll
    for (int t = 0; t < 4; ++t) {
      const int row = qi * 64 + wv * 16 + lgrp * 4 + t;
      const int col = h * DH + sub * 16 + lhalf;
      Ae[(size_t)row * AE_LD + col] = f2b(o[sub][t] / lrow[t]);
    }
}

// ---------------- SiLU gate: Ae[:, 2048+j] = silu(gate)*ff_x ----------------
__global__ void __launch_bounds__(256) ffa_kernel(const u16* __restrict__ proj,
                                                  u16* __restrict__ Ae) {
  const size_t idx = (size_t)blockIdx.x * 256 + threadIdx.x;
  const size_t e = idx * 8;
  const int row = (int)(e >> 13);   // /8192
  const int j = (int)(e & 8191);
  const u16* base = proj + (size_t)row * FUSED_OUT + FFOFF;
  U8 xr, gr, os;
  xr.v = *(const uint4*)(base + j);
  gr.v = *(const uint4*)(base + FF_INNER + j);
#pragma unroll
  for (int i = 0; i < 8; ++i) {
    const float g = b2f(gr.s[i]);
    const float sg = g / (1.f + __expf(-g));
    os.s[i] = f2b(sg * b2f(xr.s[i]));
  }
  *(uint4*)(Ae + (size_t)row * AE_LD + 2048 + j) = os.v;
}

extern "C" void kernel_launch(void* const* d_in, const int* in_sizes, int n_in,
                              void* d_out, int out_size, void* d_ws, size_t ws_size,
                              hipStream_t stream) {
  const float* x       = (const float*)d_in[0];
  const float* gamma   = (const float*)d_in[1];
  const float* w_fused = (const float*)d_in[2];
  const float* w_attn  = (const float*)d_in[3];
  const float* w_ff    = (const float*)d_in[4];
  float* out = (float*)d_out;
  char* ws = (char*)d_ws;
  u16* xn   = (u16*)(ws + WS_XN);
  u16* wfT  = (u16*)(ws + WS_WFT);
  u16* proj = (u16*)(ws + WS_PROJ);
  u16* Vt   = (u16*)(ws + WS_VT);
  u16* BtE  = (u16*)(ws + WS_BTE);   // aliases xn/wfT (dead after proj GEMM)
  u16* Ae   = (u16*)(ws + WS_AE);

  // Phase 1: LN + weight transpose(+cast) + fused projection GEMM
  ln_kernel<<<dim3(2048), dim3(256), 0, stream>>>(x, gamma, xn);
  transpose_f2b<<<dim3(584, 64), dim3(32, 8), 0, stream>>>(w_fused, wfT, FUSED_OUT, DIM);
  gemm_bt<false><<<dim3(16, 146), dim3(256), 0, stream>>>(xn, wfT, proj, DIM, DIM, DIM, FUSED_OUT);

  // Phase 2: attention + gate, into concat-K activation buffer
  transpose_u16<<<dim3(4, 64), dim3(32, 8), 0, stream>>>(proj + VOFF, Vt, FUSED_OUT, SEQ);
  transpose_f2b<<<dim3(64, 64), dim3(32, 8), 0, stream>>>(w_attn, BtE, DIM, AE_LD);
  transpose_f2b<<<dim3(64, 256), dim3(32, 8), 0, stream>>>(w_ff, BtE + 2048, DIM, AE_LD);
  attn_kernel<<<dim3(32, 16), dim3(256), 0, stream>>>(proj, Vt, Ae);
  ffa_kernel<<<dim3(8192), dim3(256), 0, stream>>>(proj, Ae);

  // Phase 3: fused (attn_out + ff_out) via one concat-K GEMM straight to d_out
  gemm_bt<true><<<dim3(16, 16), dim3(256), 0, stream>>>(Ae, BtE, out, AE_LD, AE_LD, AE_LD, DIM);
}

// Round 4
// 718.381 us; speedup vs baseline: 1.2752x; 1.1438x over previous
//
#include <hip/hip_runtime.h>
#include <hip/hip_bf16.h>

typedef unsigned short u16;
typedef __bf16 bf16x8 __attribute__((ext_vector_type(8)));
typedef float f32x4 __attribute__((ext_vector_type(4)));

#define DIM 2048
#define SEQ 2048
#define HEADS 16
#define DH 128
#define FUSED_OUT 18688   // 2048 q + 128 k + 128 v + 16384 ff
#define FF_INNER 8192
#define KOFF 2048
#define VOFF 2176
#define FFOFF 2304
#define AE_LD 10240       // 2048 attn + 8192 ffa concat-K for final GEMM

// ---- workspace layout (bytes). Total = 162,004,992 (~155 MB).
#define WS_XN   0
#define WS_WFT  8388608
#define WS_PROJ 84934656
#define WS_VT   161480704
#define WS_BTE  0
#define WS_AE   41943040

__device__ __forceinline__ float b2f(u16 u) {
  union { unsigned int i; float f; } c; c.i = ((unsigned int)u) << 16; return c.f;
}
__device__ __forceinline__ u16 f2b(float f) {  // RNE, matches np/jax bf16 cast
  union { float f; unsigned int i; } c; c.f = f;
  return (u16)((c.i + 0x7fffu + ((c.i >> 16) & 1u)) >> 16);
}
// async global->LDS, 16B per lane; LDS dest = wave-uniform base + lane*16
__device__ __forceinline__ void async16(void* lds, const void* g) {
  __builtin_amdgcn_global_load_lds((const __attribute__((address_space(1))) unsigned int*)g,
                                   (__attribute__((address_space(3))) unsigned int*)lds,
                                   16, 0, 0);
}

union U8 { uint4 v; u16 s[8]; };

// ---------------- LayerNorm: one block per row; f32 in -> bf16 out ----------------
__global__ void __launch_bounds__(256) ln_kernel(const float* __restrict__ x,
                                                 const float* __restrict__ gamma,
                                                 u16* __restrict__ xn) {
  const int row = blockIdx.x, tid = threadIdx.x;
  const int lane = tid & 63, wv = tid >> 6;
  float v[8], s1 = 0.f, s2 = 0.f;
  {
    float4 a0 = *(const float4*)(x + (size_t)row * DIM + tid * 8);
    float4 a1 = *(const float4*)(x + (size_t)row * DIM + tid * 8 + 4);
    v[0] = a0.x; v[1] = a0.y; v[2] = a0.z; v[3] = a0.w;
    v[4] = a1.x; v[5] = a1.y; v[6] = a1.z; v[7] = a1.w;
  }
#pragma unroll
  for (int i = 0; i < 8; ++i) { s1 += v[i]; s2 += v[i] * v[i]; }
#pragma unroll
  for (int off = 32; off > 0; off >>= 1) {
    s1 += __shfl_down(s1, off, 64);
    s2 += __shfl_down(s2, off, 64);
  }
  __shared__ float r1[4], r2[4];
  if (lane == 0) { r1[wv] = s1; r2[wv] = s2; }
  __syncthreads();
  s1 = r1[0] + r1[1] + r1[2] + r1[3];
  s2 = r2[0] + r2[1] + r2[2] + r2[3];
  const float inv = 1.0f / DIM;
  const float mu = s1 * inv;
  const float var = s2 * inv - mu * mu;
  const float rs = rsqrtf(var + 1e-5f);
  float4 g0 = *(const float4*)(gamma + tid * 8);
  float4 g1 = *(const float4*)(gamma + tid * 8 + 4);
  const float gm[8] = {g0.x, g0.y, g0.z, g0.w, g1.x, g1.y, g1.z, g1.w};
  U8 o;
#pragma unroll
  for (int i = 0; i < 8; ++i) o.s[i] = f2b((v[i] - mu) * rs * gm[i]);
  *(uint4*)(xn + (size_t)row * DIM + tid * 8) = o.v;
}

// ------- 64x64 transpose f32 -> bf16: out[c*ldout + r] = bf16(in[r*ldin + c]) -------
// block (64,4): 128B-coalesced stores, 256B-coalesced loads.
__global__ void __launch_bounds__(256) transpose_f2b64(const float* __restrict__ in,
                                                       u16* __restrict__ out,
                                                       int ldin, int ldout) {
  __shared__ u16 t[64][65];
  const int tx = threadIdx.x, ty = threadIdx.y;
  const int r0 = blockIdx.y * 64, c0 = blockIdx.x * 64;
#pragma unroll
  for (int i = 0; i < 16; ++i)
    t[ty + i * 4][tx] = f2b(in[(size_t)(r0 + ty + i * 4) * ldin + c0 + tx]);
  __syncthreads();
#pragma unroll
  for (int i = 0; i < 16; ++i)
    out[(size_t)(c0 + ty + i * 4) * ldout + r0 + tx] = t[tx][ty + i * 4];
}

// ------- merged w_attn/w_ff transpose into BtE (both ldin = DIM) -------
__global__ void __launch_bounds__(256) trans_wout64(const float* __restrict__ w_attn,
                                                    const float* __restrict__ w_ff,
                                                    u16* __restrict__ BtE) {
  __shared__ u16 t[64][65];
  const int tx = threadIdx.x, ty = threadIdx.y;
  const int c0 = blockIdx.x * 64;  // n (output row)
  const float* in; int r0, kout;
  if (blockIdx.y < 32) { in = w_attn; r0 = blockIdx.y * 64; kout = r0; }
  else { in = w_ff; r0 = (blockIdx.y - 32) * 64; kout = 2048 + r0; }
#pragma unroll
  for (int i = 0; i < 16; ++i)
    t[ty + i * 4][tx] = f2b(in[(size_t)(r0 + ty + i * 4) * DIM + c0 + tx]);
  __syncthreads();
#pragma unroll
  for (int i = 0; i < 16; ++i)
    BtE[(size_t)(c0 + ty + i * 4) * AE_LD + kout + tx] = t[tx][ty + i * 4];
}

// ------- 64x64 transpose bf16 -> bf16 (for V^T) -------
__global__ void __launch_bounds__(256) transpose_u16_64(const u16* __restrict__ in,
                                                        u16* __restrict__ out,
                                                        int ldin, int ldout) {
  __shared__ u16 t[64][65];
  const int tx = threadIdx.x, ty = threadIdx.y;
  const int r0 = blockIdx.y * 64, c0 = blockIdx.x * 64;
#pragma unroll
  for (int i = 0; i < 16; ++i)
    t[ty + i * 4][tx] = in[(size_t)(r0 + ty + i * 4) * ldin + c0 + tx];
  __syncthreads();
#pragma unroll
  for (int i = 0; i < 16; ++i)
    out[(size_t)(c0 + ty + i * 4) * ldout + r0 + tx] = t[tx][ty + i * 4];
}

// ---------------- GEMM: C(MxN) = A(MxK) @ Bt(NxK)^T, bf16 in, f32 acc ----------
// m97 structure: 128x128 tile, BK=64, 4 waves (2x2 of 64x64), global_load_lds w=16.
// Grid: x = M-tile (fast-varying -> consecutive blocks share the B tile), y = N-tile,
// z = K-split (each z-slab covers Ksz of K). LDS XOR-swizzled (16B block b at b^(row&7)).
// OUTMODE: 0 = bf16 store, 2 = f32 atomicAdd (split-K epilogue).
template <int OUTMODE>
__global__ void __launch_bounds__(256) gemm_bt(const u16* __restrict__ A,
                                               const u16* __restrict__ Bt,
                                               void* __restrict__ Cv,
                                               int Ksz, int lda, int ldb, int ldc) {
  __shared__ alignas(16) u16 sA[128 * 64];
  __shared__ alignas(16) u16 sB[128 * 64];
  const int tid = threadIdx.x;
  const int lane = tid & 63, wv = tid >> 6;
  const int lhalf = lane & 15, lgrp = lane >> 4;
  const int m0 = blockIdx.x * 128, n0 = blockIdx.y * 128;
  const int kbeg = blockIdx.z * Ksz, kend = kbeg + Ksz;
  const int wr = (wv >> 1) * 64, wc = (wv & 1) * 64;
  const f32x4 fzero = {0.f, 0.f, 0.f, 0.f};

  // staging map: lane covers row = c*32 + wv*8 + (lane>>3); its LDS slot is 16B-block
  // (lane&7) of that row, which holds global 16B-block ((lane&7) ^ (row&7)).
  const int srow = lane >> 3;                // row-within-8 = row&7
  const int scol = ((lane & 7) ^ srow) * 8;  // swizzled global col (u16)
  const int key = lhalf & 7;                 // fragment-read XOR key (= row&7)

  f32x4 acc[4][4];
#pragma unroll
  for (int i = 0; i < 4; ++i)
#pragma unroll
    for (int j = 0; j < 4; ++j) acc[i][j] = fzero;

  for (int k0 = kbeg; k0 < kend; k0 += 64) {
#pragma unroll
    for (int c = 0; c < 4; ++c) {
      const int row = c * 32 + wv * 8 + srow;
      const int ldsoff = (c * 4096 + wv * 1024) >> 1;  // wave-uniform LDS base (u16 idx)
      async16(&sA[ldsoff], A + (size_t)(m0 + row) * lda + k0 + scol);
      async16(&sB[ldsoff], Bt + (size_t)(n0 + row) * ldb + k0 + scol);
    }
    __syncthreads();  // waits vmcnt(0): global_load_lds drained
#pragma unroll
    for (int kk = 0; kk < 64; kk += 32) {
      bf16x8 af[4], bfr[4];
#pragma unroll
      for (int i = 0; i < 4; ++i)
        af[i] = *(const bf16x8*)&sA[(wr + i * 16 + lhalf) * 64 + ((((kk >> 3) + lgrp) ^ key) << 3)];
#pragma unroll
      for (int j = 0; j < 4; ++j)
        bfr[j] = *(const bf16x8*)&sB[(wc + j * 16 + lhalf) * 64 + ((((kk >> 3) + lgrp) ^ key) << 3)];
#pragma unroll
      for (int i = 0; i < 4; ++i)
#pragma unroll
        for (int j = 0; j < 4; ++j)
          acc[i][j] = __builtin_amdgcn_mfma_f32_16x16x32_bf16(af[i], bfr[j], acc[i][j], 0, 0, 0);
    }
    __syncthreads();
  }
  // C/D layout (verified m89/m91): col = lane&15, row = (lane>>4)*4 + reg
#pragma unroll
  for (int i = 0; i < 4; ++i)
#pragma unroll
    for (int j = 0; j < 4; ++j)
#pragma unroll
      for (int t = 0; t < 4; ++t) {
        const int row = m0 + wr + i * 16 + lgrp * 4 + t;
        const int col = n0 + wc + j * 16 + lhalf;
        if (OUTMODE == 0) ((u16*)Cv)[(size_t)row * ldc + col] = f2b(acc[i][j][t]);
        else atomicAdd((float*)Cv + (size_t)row * ldc + col, acc[i][j][t]);
      }
}

// ---------------- Flash MQA attention ----------------
// Block = 64 q-rows (4 waves x 16 rows), head = blockIdx.y, q-tile = blockIdx.x.
// Ks/Vts staged via async16 (swizzled); Ps is wave-private (s_waitcnt, no barrier).
__global__ void __launch_bounds__(256) attn_kernel(const u16* __restrict__ proj,
                                                   const u16* __restrict__ Vt,
                                                   u16* __restrict__ Ae) {
  const int h = blockIdx.y, qi = blockIdx.x;
  const int tid = threadIdx.x;
  const int lane = tid & 63, wv = tid >> 6;
  const int lhalf = lane & 15, lgrp = lane >> 4;
  const int key = lhalf & 7;

  __shared__ alignas(16) u16 Ks[128 * 128];       // K tile: [j][d], swizzled
  __shared__ alignas(16) u16 Vts[128 * 128];      // V^T tile: [d][j], swizzled
  __shared__ alignas(16) u16 Ps[4][16 * 128];     // per-wave P scratch, swizzled

  // async16 staging map: chunk = 4 rows of 256B; lane -> row (lane>>4), block (lane&15)
  const int sr = lane >> 4;                 // row within chunk
  const int sb = lane & 15;                 // LDS 16B-block within row

  // Q fragments live in regs for the whole kernel (wave's 16 rows x 128 d)
  bf16x8 aq[4];
  {
    const u16* gq = proj + (size_t)(qi * 64 + wv * 16 + lhalf) * FUSED_OUT + h * DH;
#pragma unroll
    for (int kk = 0; kk < 4; ++kk) aq[kk] = *(const bf16x8*)(gq + kk * 32 + lgrp * 8);
  }
  const f32x4 fzero = {0.f, 0.f, 0.f, 0.f};
  f32x4 o[8];
#pragma unroll
  for (int i = 0; i < 8; ++i) o[i] = fzero;
  float mrow[4] = {-__builtin_inff(), -__builtin_inff(), -__builtin_inff(), -__builtin_inff()};
  float lrow[4] = {0.f, 0.f, 0.f, 0.f};
  const float scale = 0.088388347648318447f;  // 128^-0.5
  const int jmax = (qi * 64 + 63) >> 7;

  for (int jt = 0; jt <= jmax; ++jt) {
    __syncthreads();  // prior tile's readers done before restaging
#pragma unroll
    for (int i = 0; i < 8; ++i) {
      const int ch = wv * 8 + i;            // chunk 0..31 (1KB each)
      const int row = ch * 4 + sr;
      const int gb = sb ^ (row & 7);        // swizzled global 16B-block
      async16(&Ks[ch * 512], proj + (size_t)(jt * 128 + row) * FUSED_OUT + KOFF + gb * 8);
      async16(&Vts[ch * 512], Vt + (size_t)row * SEQ + jt * 128 + gb * 8);
    }
    __syncthreads();  // staging drained
    // S (16x128) = Q_wave @ K^T
    f32x4 s[8];
#pragma unroll
    for (int sub = 0; sub < 8; ++sub) {
      f32x4 a = fzero;
#pragma unroll
      for (int kk = 0; kk < 4; ++kk) {
        bf16x8 bk = *(const bf16x8*)&Ks[(sub * 16 + lhalf) * 128 + (((kk * 4 + lgrp) ^ key) << 3)];
        a = __builtin_amdgcn_mfma_f32_16x16x32_bf16(aq[kk], bk, a, 0, 0, 0);
      }
      s[sub] = a;
    }
    const int row_g = qi * 64 + wv * 16 + lgrp * 4;  // + t
    const int col_b = jt * 128 + lhalf;              // + sub*16
#pragma unroll
    for (int t = 0; t < 4; ++t) {
      float mx = -__builtin_inff();
#pragma unroll
      for (int sub = 0; sub < 8; ++sub) {
        float v = s[sub][t] * scale;
        if (col_b + sub * 16 > row_g + t) v = -__builtin_inff();  // causal
        s[sub][t] = v;
        mx = fmaxf(mx, v);
      }
      mx = fmaxf(mx, __shfl_xor(mx, 1, 64));
      mx = fmaxf(mx, __shfl_xor(mx, 2, 64));
      mx = fmaxf(mx, __shfl_xor(mx, 4, 64));
      mx = fmaxf(mx, __shfl_xor(mx, 8, 64));
      const float mnew = fmaxf(mrow[t], mx);
      const float alpha = __expf(mrow[t] - mnew);  // first iter: exp(-inf)=0
      mrow[t] = mnew;
      float ls = 0.f;
#pragma unroll
      for (int sub = 0; sub < 8; ++sub) {
        const float p = __expf(s[sub][t] - mnew);
        s[sub][t] = p;
        ls += p;
      }
      ls += __shfl_xor(ls, 1, 64);
      ls += __shfl_xor(ls, 2, 64);
      ls += __shfl_xor(ls, 4, 64);
      ls += __shfl_xor(ls, 8, 64);
      lrow[t] = lrow[t] * alpha + ls;
      // C-layout -> A-layout via LDS (m120), swizzled store
      const int prow = lgrp * 4 + t;
      const int pkey = prow & 7;
#pragma unroll
      for (int sub = 0; sub < 8; ++sub) {
        o[sub][t] *= alpha;
        const int b = sub * 2 + (lhalf >> 3);
        Ps[wv][prow * 128 + ((b ^ pkey) << 3) + (lhalf & 7)] = f2b(s[sub][t]);
      }
    }
    // Ps is wave-private: per-wave LDS drain is enough (no __syncthreads)
    asm volatile("s_waitcnt lgkmcnt(0)" ::: "memory");
    // O += P (16x128) @ V (128x128): A from Ps, B^T from Vts
#pragma unroll
    for (int kk = 0; kk < 4; ++kk) {
      bf16x8 ap = *(const bf16x8*)&Ps[wv][lhalf * 128 + (((kk * 4 + lgrp) ^ key) << 3)];
#pragma unroll
      for (int sub = 0; sub < 8; ++sub) {
        bf16x8 bv = *(const bf16x8*)&Vts[(sub * 16 + lhalf) * 128 + (((kk * 4 + lgrp) ^ key) << 3)];
        o[sub] = __builtin_amdgcn_mfma_f32_16x16x32_bf16(ap, bv, o[sub], 0, 0, 0);
      }
    }
  }
#pragma unroll
  for (int sub = 0; sub < 8; ++sub)
#pragma unroll
    for (int t = 0; t < 4; ++t) {
      const int row = qi * 64 + wv * 16 + lgrp * 4 + t;
      const int col = h * DH + sub * 16 + lhalf;
      Ae[(size_t)row * AE_LD + col] = f2b(o[sub][t] / lrow[t]);
    }
}

// ---------------- SiLU gate: Ae[:, 2048+j] = silu(gate)*ff_x ----------------
__global__ void __launch_bounds__(256) ffa_kernel(const u16* __restrict__ proj,
                                                  u16* __restrict__ Ae) {
  const size_t idx = (size_t)blockIdx.x * 256 + threadIdx.x;
  const size_t e = idx * 8;
  const int row = (int)(e >> 13);   // /8192
  const int j = (int)(e & 8191);
  const u16* base = proj + (size_t)row * FUSED_OUT + FFOFF;
  U8 xr, gr, os;
  xr.v = *(const uint4*)(base + j);
  gr.v = *(const uint4*)(base + FF_INNER + j);
#pragma unroll
  for (int i = 0; i < 8; ++i) {
    const float g = b2f(gr.s[i]);
    const float sg = g / (1.f + __expf(-g));
    os.s[i] = f2b(sg * b2f(xr.s[i]));
  }
  *(uint4*)(Ae + (size_t)row * AE_LD + 2048 + j) = os.v;
}

extern "C" void kernel_launch(void* const* d_in, const int* in_sizes, int n_in,
                              void* d_out, int out_size, void* d_ws, size_t ws_size,
                              hipStream_t stream) {
  const float* x       = (const float*)d_in[0];
  const float* gamma   = (const float*)d_in[1];
  const float* w_fused = (const float*)d_in[2];
  const float* w_attn  = (const float*)d_in[3];
  const float* w_ff    = (const float*)d_in[4];
  float* out = (float*)d_out;
  char* ws = (char*)d_ws;
  u16* xn   = (u16*)(ws + WS_XN);
  u16* wfT  = (u16*)(ws + WS_WFT);
  u16* proj = (u16*)(ws + WS_PROJ);
  u16* Vt   = (u16*)(ws + WS_VT);
  u16* BtE  = (u16*)(ws + WS_BTE);   // aliases xn/wfT (dead after proj GEMM)
  u16* Ae   = (u16*)(ws + WS_AE);

  // zero d_out for the split-K atomic epilogue (harness poisons it with 0xAA)
  hipMemsetAsync(d_out, 0, (size_t)out_size * sizeof(float), stream);

  // Phase 1: LN + weight transpose(+cast) + fused projection GEMM
  ln_kernel<<<dim3(2048), dim3(256), 0, stream>>>(x, gamma, xn);
  transpose_f2b64<<<dim3(292, 32), dim3(64, 4), 0, stream>>>(w_fused, wfT, FUSED_OUT, DIM);
  gemm_bt<0><<<dim3(16, 146, 1), dim3(256), 0, stream>>>(xn, wfT, proj, DIM, DIM, DIM, FUSED_OUT);

  // Phase 2: attention + gate, into concat-K activation buffer
  transpose_u16_64<<<dim3(2, 32), dim3(64, 4), 0, stream>>>(proj + VOFF, Vt, FUSED_OUT, SEQ);
  trans_wout64<<<dim3(32, 160), dim3(64, 4), 0, stream>>>(w_attn, w_ff, BtE);
  attn_kernel<<<dim3(32, 16), dim3(256), 0, stream>>>(proj, Vt, Ae);
  ffa_kernel<<<dim3(8192), dim3(256), 0, stream>>>(proj, Ae);

  // Phase 3: fused (attn_out + ff_out) via one concat-K split-K GEMM -> atomic f32
  gemm_bt<2><<<dim3(16, 16, 2), dim3(256), 0, stream>>>(Ae, BtE, out, AE_LD / 2, AE_LD, AE_LD, DIM);
}